// Round 1
// baseline (392.261 us; speedup 1.0000x reference)
//
#include <hip/hip_runtime.h>
#include <stdint.h>

typedef __bf16 bf16x8 __attribute__((ext_vector_type(8)));
typedef float f32x4 __attribute__((ext_vector_type(4)));
typedef unsigned short u16;
typedef unsigned int u32;

union V16 { uint4 u; u16 s[8]; bf16x8 b; };

__device__ __forceinline__ u16 f2bf(float f) {
    u32 u = __builtin_bit_cast(u32, f);
    u = (u + 0x7fffu + ((u >> 16) & 1u)) >> 16;
    return (u16)u;
}

// ---------------- weight prep: fp32 -> bf16, transposed to (N x K) ----------------
// Wq,Wk (H,E,Dh) -> wqkT[c][e], c = h*64+d for Q (c<1024), K at c-1024
__global__ void prep_qk_kernel(const float* __restrict__ Wq, const float* __restrict__ Wk,
                               u16* __restrict__ dst) {
    int idx = blockIdx.x * 256 + threadIdx.x;   // idx = c*1024 + e
    int c = idx >> 10, e = idx & 1023;
    const float* src = (c < 1024) ? Wq : Wk;
    int cc = c & 1023;
    int h = cc >> 6, d = cc & 63;
    dst[idx] = f2bf(src[(size_t)(h * 1024 + e) * 64 + d]);
}

// src is (K x N) row-major; dst is (N x K): dst[n*K+k] = src[k*N+n]
__global__ void prep_t_kernel(const float* __restrict__ src, u16* __restrict__ dst,
                              int N, int K) {
    int idx = blockIdx.x * 256 + threadIdx.x;   // idx = n*K + k
    int n = idx / K, k = idx - n * K;
    dst[idx] = f2bf(src[(size_t)k * N + n]);
}

// ---------------- layernorm: fp32 (rows x 1024) -> bf16 ----------------
__global__ __launch_bounds__(256)
void ln_kernel(const float* __restrict__ x, u16* __restrict__ out,
               const float* __restrict__ gw, const float* __restrict__ bw) {
    __shared__ float red[8];
    int row = blockIdx.x, t = threadIdx.x;
    float4 v = reinterpret_cast<const float4*>(x + (size_t)row * 1024)[t];
    float s = v.x + v.y + v.z + v.w;
    float sq = v.x * v.x + v.y * v.y + v.z * v.z + v.w * v.w;
    for (int o = 32; o > 0; o >>= 1) { s += __shfl_down(s, o); sq += __shfl_down(sq, o); }
    if ((t & 63) == 0) { red[t >> 6] = s; red[4 + (t >> 6)] = sq; }
    __syncthreads();
    float S  = red[0] + red[1] + red[2] + red[3];
    float SQ = red[4] + red[5] + red[6] + red[7];
    float mean = S * (1.f / 1024.f);
    float var  = SQ * (1.f / 1024.f) - mean * mean;
    float rstd = rsqrtf(var + 1e-5f);
    float4 g4 = reinterpret_cast<const float4*>(gw)[t];
    float4 b4 = reinterpret_cast<const float4*>(bw)[t];
    ushort4 o;
    o.x = f2bf((v.x - mean) * rstd * g4.x + b4.x);
    o.y = f2bf((v.y - mean) * rstd * g4.y + b4.y);
    o.z = f2bf((v.z - mean) * rstd * g4.z + b4.z);
    o.w = f2bf((v.w - mean) * rstd * g4.w + b4.w);
    reinterpret_cast<ushort4*>(out + (size_t)row * 1024)[t] = o;
}

// ---------------- GEMM: C(MxN) = A(MxK) * B^T(NxK), bf16 in, fp32 acc ----------------
// EPI: 0 = plain -> bf16; 1 = +bias +residual -> fp32; 2 = +bias +relu -> bf16
template<int EPI, typename OT>
__global__ __launch_bounds__(256)
void gemm_bt(const u16* __restrict__ A, const u16* __restrict__ B,
             OT* __restrict__ C, const float* __restrict__ bias,
             const float* __restrict__ res, int K, int N) {
    __shared__ u16 Al[128 * 64];
    __shared__ u16 Bl[128 * 64];
    const int t = threadIdx.x;
    const int lane = t & 63;
    const int w = t >> 6;
    const int wm = w >> 1, wn = w & 1;
    const int l15 = lane & 15, g = lane >> 4;
    const int row0 = blockIdx.y * 128, col0 = blockIdx.x * 128;

    f32x4 acc[4][4] = {};

    const int nkb = K >> 6;
    for (int kb = 0; kb < nkb; ++kb) {
        #pragma unroll
        for (int i = 0; i < 4; ++i) {
            int c = t + i * 256;
            int r = c >> 3, kc = c & 7;
            uint4 va = *reinterpret_cast<const uint4*>(A + (size_t)(row0 + r) * K + kb * 64 + kc * 8);
            uint4 vb = *reinterpret_cast<const uint4*>(B + (size_t)(col0 + r) * K + kb * 64 + kc * 8);
            int ba = (r * 128 + kc * 16) ^ ((r & 7) << 4);  // XOR swizzle, 16B granules
            *reinterpret_cast<uint4*>(reinterpret_cast<char*>(Al) + ba) = va;
            *reinterpret_cast<uint4*>(reinterpret_cast<char*>(Bl) + ba) = vb;
        }
        __syncthreads();
        #pragma unroll
        for (int s = 0; s < 2; ++s) {
            bf16x8 af[4], bfr[4];
            #pragma unroll
            for (int mi = 0; mi < 4; ++mi) {
                int rl = wm * 64 + mi * 16 + l15;
                int ba = rl * 128 + ((s * 64 + g * 16) ^ ((rl & 7) << 4));
                af[mi] = *reinterpret_cast<const bf16x8*>(reinterpret_cast<const char*>(Al) + ba);
            }
            #pragma unroll
            for (int ni = 0; ni < 4; ++ni) {
                int rl = wn * 64 + ni * 16 + l15;
                int ba = rl * 128 + ((s * 64 + g * 16) ^ ((rl & 7) << 4));
                bfr[ni] = *reinterpret_cast<const bf16x8*>(reinterpret_cast<const char*>(Bl) + ba);
            }
            #pragma unroll
            for (int mi = 0; mi < 4; ++mi)
                #pragma unroll
                for (int ni = 0; ni < 4; ++ni)
                    acc[mi][ni] = __builtin_amdgcn_mfma_f32_16x16x32_bf16(af[mi], bfr[ni], acc[mi][ni], 0, 0, 0);
        }
        __syncthreads();
    }

    #pragma unroll
    for (int mi = 0; mi < 4; ++mi) {
        #pragma unroll
        for (int ni = 0; ni < 4; ++ni) {
            int gcol = col0 + wn * 64 + ni * 16 + l15;
            #pragma unroll
            for (int r = 0; r < 4; ++r) {
                int grow = row0 + wm * 64 + mi * 16 + g * 4 + r;  // D: row=4*(lane>>4)+reg, col=lane&15
                float v = acc[mi][ni][r];
                if constexpr (EPI >= 1) v += bias[gcol];
                if constexpr (EPI == 1) v += res[(size_t)grow * N + gcol];
                if constexpr (EPI == 2) v = fmaxf(v, 0.f);
                if constexpr (sizeof(OT) == 4) C[(size_t)grow * N + gcol] = v;
                else                           C[(size_t)grow * N + gcol] = f2bf(v);
            }
        }
    }
}

// ---------------- causal flash attention, V == K ----------------
// qk: (4096 x 2048) bf16, row = b*2048+s, cols [0,1024)=Q(h*64+d), [1024,2048)=K
// out: (4096 x 1024) bf16, col = h*64+d
// 1 wave per 16 q-rows. scores computed transposed: D[k][q] = mfma(Kfrag, Qfrag)
__global__ __launch_bounds__(64)
void attn_kernel(const u16* __restrict__ qk, u16* __restrict__ out) {
    __shared__ u16 ktl[64 * 32];  // K^T tile: [d][k_local]
    const int lane = threadIdx.x;
    const int l15 = lane & 15, g = lane >> 4;
    const int bh = blockIdx.y;
    const int b = bh >> 4, h = bh & 15;
    const int q0 = blockIdx.x * 16;
    const int qg = q0 + l15;

    const u16* Qb = qk + (size_t)b * 2048 * 2048 + h * 64;
    const u16* Kb = Qb + 1024;

    V16 qa[2];
    #pragma unroll
    for (int s = 0; s < 2; ++s)
        qa[s].u = *reinterpret_cast<const uint4*>(Qb + (size_t)(q0 + l15) * 2048 + s * 32 + g * 8);

    f32x4 ot[4] = {};                     // O^T: rows d (4 frags of 16), cols q = lane&15
    float m_run = -3.0e38f, l_run = 0.f;
    const int nkt = (q0 + 47) >> 5;       // k-tiles of 32 covering k < q0+16

    for (int kt = 0; kt < nkt; ++kt) {
        V16 ka[2][2];
        #pragma unroll
        for (int m = 0; m < 2; ++m)
            #pragma unroll
            for (int s = 0; s < 2; ++s)
                ka[m][s].u = *reinterpret_cast<const uint4*>(
                    Kb + (size_t)(kt * 32 + m * 16 + l15) * 2048 + s * 32 + g * 8);
        __syncthreads();   // previous iteration's LDS reads done
        #pragma unroll
        for (int m = 0; m < 2; ++m)
            #pragma unroll
            for (int s = 0; s < 2; ++s)
                #pragma unroll
                for (int j = 0; j < 8; ++j)
                    ktl[(s * 32 + g * 8 + j) * 32 + m * 16 + l15] = ka[m][s].s[j];
        __syncthreads();   // K^T visible

        f32x4 z = {};
        f32x4 st0 = __builtin_amdgcn_mfma_f32_16x16x32_bf16(ka[0][0].b, qa[0].b, z, 0, 0, 0);
        st0 = __builtin_amdgcn_mfma_f32_16x16x32_bf16(ka[0][1].b, qa[1].b, st0, 0, 0, 0);
        f32x4 st1 = __builtin_amdgcn_mfma_f32_16x16x32_bf16(ka[1][0].b, qa[0].b, z, 0, 0, 0);
        st1 = __builtin_amdgcn_mfma_f32_16x16x32_bf16(ka[1][1].b, qa[1].b, st1, 0, 0, 0);

        float ps[2][4];
        float mt = -3.0e38f;
        #pragma unroll
        for (int m = 0; m < 2; ++m)
            #pragma unroll
            for (int r = 0; r < 4; ++r) {
                float v = (m ? st1[r] : st0[r]) * 0.125f;
                int kgl = kt * 32 + m * 16 + g * 4 + r;   // D row = k_local = 4*(lane>>4)+reg
                v = (kgl <= qg) ? v : -3.0e38f;
                ps[m][r] = v;
                mt = fmaxf(mt, v);
            }
        mt = fmaxf(mt, __shfl_xor(mt, 16));
        mt = fmaxf(mt, __shfl_xor(mt, 32));
        float mn = fmaxf(m_run, mt);
        float alpha = __expf(m_run - mn);
        float rs = 0.f;
        #pragma unroll
        for (int m = 0; m < 2; ++m)
            #pragma unroll
            for (int r = 0; r < 4; ++r) {
                float p = (ps[m][r] > -1.0e38f) ? __expf(ps[m][r] - mn) : 0.f;
                ps[m][r] = p;
                rs += p;
            }
        rs += __shfl_xor(rs, 16);
        rs += __shfl_xor(rs, 32);
        l_run = l_run * alpha + rs;
        m_run = mn;
        #pragma unroll
        for (int f = 0; f < 4; ++f) ot[f] = ot[f] * alpha;   // alpha is per-q = lane&15 = O^T col

        // P^T -> B-frag (col=q=lane&15, kk=8g+j) via cross-lane shuffles
        V16 pb;
        #pragma unroll
        for (int j = 0; j < 8; ++j) {
            int src = l15 + 16 * (2 * (g & 1) + (j >> 2));
            float v0 = __shfl(ps[0][j & 3], src);
            float v1 = __shfl(ps[1][j & 3], src);
            pb.b[j] = (__bf16)((g >= 2) ? v1 : v0);
        }
        // O^T += K^T(d x k) * P(k x q)
        #pragma unroll
        for (int f = 0; f < 4; ++f) {
            const bf16x8 av = *reinterpret_cast<const bf16x8*>(&ktl[(f * 16 + l15) * 32 + g * 8]);
            ot[f] = __builtin_amdgcn_mfma_f32_16x16x32_bf16(av, pb.b, ot[f], 0, 0, 0);
        }
    }

    float inv = 1.f / l_run;
    u16* op = out + (size_t)(b * 2048 + q0 + l15) * 1024 + h * 64;
    #pragma unroll
    for (int f = 0; f < 4; ++f)
        #pragma unroll
        for (int r = 0; r < 4; ++r)
            op[f * 16 + g * 4 + r] = f2bf(ot[f][r] * inv);
}

// ---------------- launcher ----------------
extern "C" void kernel_launch(void* const* d_in, const int* in_sizes, int n_in,
                              void* d_out, int out_size, void* d_ws, size_t ws_size,
                              hipStream_t stream) {
    const float* x     = (const float*)d_in[0];
    const float* Wq    = (const float*)d_in[1];
    const float* Wk    = (const float*)d_in[2];
    const float* Wproj = (const float*)d_in[3];
    const float* bproj = (const float*)d_in[4];
    const float* ln1g  = (const float*)d_in[5];
    const float* ln1b  = (const float*)d_in[6];
    const float* ln2g  = (const float*)d_in[7];
    const float* ln2b  = (const float*)d_in[8];
    const float* W1    = (const float*)d_in[9];
    const float* b1    = (const float*)d_in[10];
    const float* W2    = (const float*)d_in[11];
    const float* b2    = (const float*)d_in[12];

    char* ws = (char*)d_ws;
    u16*   wqkT   = (u16*)(ws + 0);          //  4 MiB: 2048x1024
    u16*   wprojT = (u16*)(ws + 4194304);    //  2 MiB: 1024x1024
    u16*   w1T    = (u16*)(ws + 6291456);    //  8 MiB: 4096x1024
    u16*   w2T    = (u16*)(ws + 14680064);   //  8 MiB: 1024x4096
    u16*   hbuf   = (u16*)(ws + 23068672);   //  8 MiB: 4096x1024 (LN1 out, later LN2 out)
    float* xmid   = (float*)(ws + 31457280); // 16 MiB: 4096x1024 fp32
    u16*   qk     = (u16*)(ws + 48234496);   // 16 MiB: 4096x2048
    u16*   attnb  = (u16*)(ws + 65011712);   //  8 MiB: 4096x1024
    u16*   ff     = (u16*)(ws + 48234496);   // 32 MiB: 4096x4096, aliases qk+attnb (dead by then)

    // weight prep
    prep_qk_kernel<<<8192, 256, 0, stream>>>(Wq, Wk, wqkT);
    prep_t_kernel<<<4096, 256, 0, stream>>>(Wproj, wprojT, 1024, 1024);
    prep_t_kernel<<<16384, 256, 0, stream>>>(W1, w1T, 4096, 1024);
    prep_t_kernel<<<16384, 256, 0, stream>>>(W2, w2T, 1024, 4096);

    // LN1
    ln_kernel<<<4096, 256, 0, stream>>>(x, hbuf, ln1g, ln1b);
    // Q|K projection: (4096x1024)x(1024x2048) -> bf16
    gemm_bt<0, u16><<<dim3(16, 32), 256, 0, stream>>>(hbuf, wqkT, qk, nullptr, nullptr, 1024, 2048);
    // causal attention (V == K)
    attn_kernel<<<dim3(128, 32), 64, 0, stream>>>(qk, attnb);
    // x = x + attn @ Wproj + bproj   (fp32 out)
    gemm_bt<1, float><<<dim3(8, 32), 256, 0, stream>>>(attnb, wprojT, xmid, bproj, x, 1024, 1024);
    // LN2
    ln_kernel<<<4096, 256, 0, stream>>>(xmid, hbuf, ln2g, ln2b);
    // ff = relu(h2 @ W1 + b1)  (bf16 out)
    gemm_bt<2, u16><<<dim3(32, 32), 256, 0, stream>>>(hbuf, w1T, ff, b1, nullptr, 1024, 4096);
    // out = xmid + ff @ W2 + b2  (fp32 out)
    gemm_bt<1, float><<<dim3(8, 32), 256, 0, stream>>>(ff, w2T, (float*)d_out, b2, xmid, 4096, 1024);
}

// Round 2
// 274.786 us; speedup vs baseline: 1.4275x; 1.4275x over previous
//
#include <hip/hip_runtime.h>
#include <stdint.h>

typedef __bf16 bf16x8 __attribute__((ext_vector_type(8)));
typedef float f32x4 __attribute__((ext_vector_type(4)));
typedef float f32x16 __attribute__((ext_vector_type(16)));
typedef unsigned short u16;
typedef unsigned int u32;

__device__ __forceinline__ u16 f2bf(float f) {
    u32 u = __builtin_bit_cast(u32, f);
    u = (u + 0x7fffu + ((u >> 16) & 1u)) >> 16;
    return (u16)u;
}

__device__ __forceinline__ void gload16(const u16* g, u16* l) {
    __builtin_amdgcn_global_load_lds(
        (const __attribute__((address_space(1))) unsigned int*)g,
        (__attribute__((address_space(3))) unsigned int*)l,
        16, 0, 0);
}

// ---------------- tiled transpose-convert: src fp32 (Z x R x C) -> dst bf16 (Z x C x R) ----------------
__global__ __launch_bounds__(256)
void prep_t_kernel(const float* __restrict__ src, u16* __restrict__ dst, int R, int C) {
    __shared__ u16 tile[64 * 64];
    const int t = threadIdx.x;
    const int c0 = blockIdx.x * 64, r0 = blockIdx.y * 64;
    const size_t mbase = (size_t)blockIdx.z * R * C;
    {
        const int r = t >> 2, j4 = t & 3;
        #pragma unroll
        for (int j = 0; j < 4; ++j) {
            int c = j4 * 4 + j * 16;
            float4 v = *reinterpret_cast<const float4*>(src + mbase + (size_t)(r0 + r) * C + c0 + c);
            tile[(c + 0) * 64 + (r ^ (((c + 0) & 7) * 8))] = f2bf(v.x);
            tile[(c + 1) * 64 + (r ^ (((c + 1) & 7) * 8))] = f2bf(v.y);
            tile[(c + 2) * 64 + (r ^ (((c + 2) & 7) * 8))] = f2bf(v.z);
            tile[(c + 3) * 64 + (r ^ (((c + 3) & 7) * 8))] = f2bf(v.w);
        }
    }
    __syncthreads();
    {
        const int cc = t >> 2, j4 = t & 3;
        const int sw = (cc & 7) * 8;
        #pragma unroll
        for (int j2 = 0; j2 < 4; ++j2) {
            int rbase = j4 * 16 + j2 * 4;
            ushort4 o;
            o.x = tile[cc * 64 + ((rbase + 0) ^ sw)];
            o.y = tile[cc * 64 + ((rbase + 1) ^ sw)];
            o.z = tile[cc * 64 + ((rbase + 2) ^ sw)];
            o.w = tile[cc * 64 + ((rbase + 3) ^ sw)];
            *reinterpret_cast<ushort4*>(dst + mbase + (size_t)(c0 + cc) * R + r0 + rbase) = o;
        }
    }
}

// ---------------- layernorm: fp32 (rows x 1024) -> bf16 ----------------
__global__ __launch_bounds__(256)
void ln_kernel(const float* __restrict__ x, u16* __restrict__ out,
               const float* __restrict__ gw, const float* __restrict__ bw) {
    __shared__ float red[8];
    int row = blockIdx.x, t = threadIdx.x;
    float4 v = reinterpret_cast<const float4*>(x + (size_t)row * 1024)[t];
    float s = v.x + v.y + v.z + v.w;
    float sq = v.x * v.x + v.y * v.y + v.z * v.z + v.w * v.w;
    for (int o = 32; o > 0; o >>= 1) { s += __shfl_down(s, o); sq += __shfl_down(sq, o); }
    if ((t & 63) == 0) { red[t >> 6] = s; red[4 + (t >> 6)] = sq; }
    __syncthreads();
    float S  = red[0] + red[1] + red[2] + red[3];
    float SQ = red[4] + red[5] + red[6] + red[7];
    float mean = S * (1.f / 1024.f);
    float var  = SQ * (1.f / 1024.f) - mean * mean;
    float rstd = rsqrtf(var + 1e-5f);
    float4 g4 = reinterpret_cast<const float4*>(gw)[t];
    float4 b4 = reinterpret_cast<const float4*>(bw)[t];
    ushort4 o;
    o.x = f2bf((v.x - mean) * rstd * g4.x + b4.x);
    o.y = f2bf((v.y - mean) * rstd * g4.y + b4.y);
    o.z = f2bf((v.z - mean) * rstd * g4.z + b4.z);
    o.w = f2bf((v.w - mean) * rstd * g4.w + b4.w);
    reinterpret_cast<ushort4*>(out + (size_t)row * 1024)[t] = o;
}

// ---------------- GEMM: C(MxN) = A(MxK) * B^T(NxK), bf16 in, fp32 acc ----------------
// EPI: 1 = +bias +residual -> fp32; 2 = +bias +relu -> bf16; 3 = plain -> bf16, plus
//      transposed copy of cols>=1024 into ktr (K^T for attention)
template<int EPI, typename OT>
__global__ __launch_bounds__(256)
void gemm_bt(const u16* __restrict__ A, const u16* __restrict__ B,
             OT* __restrict__ C, const float* __restrict__ bias,
             const float* __restrict__ res, int K, int N, u16* __restrict__ ktr) {
    __shared__ u16 Al[128 * 64];
    __shared__ u16 Bl[128 * 64];
    const int t = threadIdx.x;
    const int lane = t & 63;
    const int w = t >> 6;
    const int wm = w >> 1, wn = w & 1;
    const int l15 = lane & 15, gq = lane >> 4;
    const int row0 = blockIdx.y * 128, col0 = blockIdx.x * 128;

    f32x4 acc[4][4] = {};

    const int nkb = K >> 6;
    for (int kb = 0; kb < nkb; ++kb) {
        #pragma unroll
        for (int i = 0; i < 4; ++i) {
            int slot = i * 256 + t;
            int r = slot >> 3;
            int g = (slot & 7) ^ (r & 7);       // pre-swizzled source granule
            gload16(A + (size_t)(row0 + r) * K + kb * 64 + g * 8, Al + slot * 8);
            gload16(B + (size_t)(col0 + r) * K + kb * 64 + g * 8, Bl + slot * 8);
        }
        __syncthreads();
        #pragma unroll
        for (int s = 0; s < 2; ++s) {
            bf16x8 af[4], bfr[4];
            #pragma unroll
            for (int mi = 0; mi < 4; ++mi) {
                int rl = wm * 64 + mi * 16 + l15;
                int ba = rl * 128 + ((s * 64 + gq * 16) ^ ((rl & 7) << 4));
                af[mi] = *reinterpret_cast<const bf16x8*>(reinterpret_cast<const char*>(Al) + ba);
            }
            #pragma unroll
            for (int ni = 0; ni < 4; ++ni) {
                int rl = wn * 64 + ni * 16 + l15;
                int ba = rl * 128 + ((s * 64 + gq * 16) ^ ((rl & 7) << 4));
                bfr[ni] = *reinterpret_cast<const bf16x8*>(reinterpret_cast<const char*>(Bl) + ba);
            }
            #pragma unroll
            for (int mi = 0; mi < 4; ++mi)
                #pragma unroll
                for (int ni = 0; ni < 4; ++ni)
                    acc[mi][ni] = __builtin_amdgcn_mfma_f32_16x16x32_bf16(af[mi], bfr[ni], acc[mi][ni], 0, 0, 0);
        }
        __syncthreads();
    }

    #pragma unroll
    for (int mi = 0; mi < 4; ++mi) {
        #pragma unroll
        for (int ni = 0; ni < 4; ++ni) {
            int gcol = col0 + wn * 64 + ni * 16 + l15;
            int grow0 = row0 + wm * 64 + mi * 16 + gq * 4;
            #pragma unroll
            for (int r = 0; r < 4; ++r) {
                int grow = grow0 + r;
                float v = acc[mi][ni][r];
                if constexpr (EPI == 1 || EPI == 2) v += bias[gcol];
                if constexpr (EPI == 1) v += res[(size_t)grow * N + gcol];
                if constexpr (EPI == 2) v = fmaxf(v, 0.f);
                if constexpr (sizeof(OT) == 4) C[(size_t)grow * N + gcol] = v;
                else                           C[(size_t)grow * N + gcol] = f2bf(v);
            }
            if constexpr (EPI == 3) {
                if (gcol >= 1024) {   // K columns: also write K^T [hd][b*2048+s]
                    ushort4 kt4;
                    kt4.x = f2bf(acc[mi][ni][0]);
                    kt4.y = f2bf(acc[mi][ni][1]);
                    kt4.z = f2bf(acc[mi][ni][2]);
                    kt4.w = f2bf(acc[mi][ni][3]);
                    *reinterpret_cast<ushort4*>(ktr + (size_t)(gcol - 1024) * 4096 + grow0) = kt4;
                }
            }
        }
    }
}

// ---------------- causal flash attention, V == K, 4 waves x 32 q-rows ----------------
// qk:  (4096 x 2048) bf16, row = b*2048+s, cols [0,1024)=Q(h*64+d), [1024,2048)=K
// ktr: (1024 x 4096) bf16, row = h*64+d, col = b*2048+k   (K^T)
// out: (4096 x 1024) bf16, col = h*64+d
__global__ __launch_bounds__(256)
void attn_kernel(const u16* __restrict__ qk, const u16* __restrict__ ktr, u16* __restrict__ out) {
    __shared__ u16 Kl[2][64 * 64];   // K rows  [k][d], swizzled
    __shared__ u16 Tl[2][64 * 64];   // K^T     [d][k], swizzled
    const int t = threadIdx.x;
    const int lane = t & 63;
    const int w = t >> 6;
    const int l31 = lane & 31, hi = lane >> 5;
    const int flat = blockIdx.x;
    const int bh = flat & 31;
    const int tt = flat >> 5;                      // 0..15
    const int qb = (tt < 8) ? tt : 23 - tt;        // pair heavy+light on same CU
    const int b = bh >> 4, h = bh & 15;
    const int q0w = qb * 128 + w * 32;
    const int q = q0w + l31;
    const u16* Qp = qk + (size_t)b * 2048 * 2048 + h * 64;
    const u16* Kp = Qp + 1024;
    const u16* Tp = ktr + (size_t)h * 64 * 4096 + (size_t)b * 2048;

    bf16x8 qf[4];
    #pragma unroll
    for (int s = 0; s < 4; ++s)
        qf[s] = *reinterpret_cast<const bf16x8*>(Qp + (size_t)q * 2048 + s * 16 + hi * 8);

    f32x16 oacc[2] = {};
    float m_run = -3.0e38f, l_run = 0.f;
    const int qwmax = q0w + 31;
    const int nt = (qb * 128 + 128) >> 6;          // number of 64-wide k stages

    // stage k-tile 0
    {
        #pragma unroll
        for (int i = 0; i < 2; ++i) {
            int slot = i * 256 + t;
            int r = slot >> 3;
            int g = (slot & 7) ^ (r & 7);
            gload16(Kp + (size_t)r * 2048 + g * 8, &Kl[0][0] + slot * 8);
            gload16(Tp + (size_t)r * 4096 + g * 8, &Tl[0][0] + slot * 8);
        }
    }

    for (int kt = 0; kt < nt; ++kt) {
        const int cur = kt & 1;
        __syncthreads();
        if (kt + 1 < nt) {
            int k0 = (kt + 1) * 64;
            #pragma unroll
            for (int i = 0; i < 2; ++i) {
                int slot = i * 256 + t;
                int r = slot >> 3;
                int g = (slot & 7) ^ (r & 7);
                gload16(Kp + (size_t)(k0 + r) * 2048 + g * 8, &Kl[cur ^ 1][0] + slot * 8);
                gload16(Tp + (size_t)r * 4096 + k0 + g * 8, &Tl[cur ^ 1][0] + slot * 8);
            }
        }
        const u16* kl = &Kl[cur][0];
        const u16* tl = &Tl[cur][0];
        #pragma unroll
        for (int s2 = 0; s2 < 2; ++s2) {
            const int ks = s2 * 32;
            const int kbase = kt * 64 + ks;
            if (kbase > qwmax) continue;           // fully masked for this wave
            // ---- scores: S^T[k][q] = K * Q  (32x32, d=64 via 4 mfmas) ----
            f32x16 st = {};
            #pragma unroll
            for (int s = 0; s < 4; ++s) {
                int r = ks + l31;
                int col = (16 * s + 8 * hi) ^ ((r & 7) * 8);
                bf16x8 kf = *reinterpret_cast<const bf16x8*>(kl + r * 64 + col);
                st = __builtin_amdgcn_mfma_f32_32x32x16_bf16(kf, qf[s], st, 0, 0, 0);
            }
            // ---- mask + online softmax (lane owns q = q0w + l31) ----
            float p[16];
            float mt = -3.0e38f;
            if (kbase + 31 <= q0w) {               // interior: no masking needed
                #pragma unroll
                for (int i = 0; i < 16; ++i) { p[i] = st[i] * 0.125f; mt = fmaxf(mt, p[i]); }
            } else {
                #pragma unroll
                for (int i = 0; i < 16; ++i) {
                    int kloc = (i & 3) + 8 * (i >> 2) + 4 * hi;
                    float v = st[i] * 0.125f;
                    v = (kbase + kloc <= q) ? v : -3.0e38f;
                    p[i] = v;
                    mt = fmaxf(mt, v);
                }
            }
            mt = fmaxf(mt, __shfl_xor(mt, 32));
            float mn = fmaxf(m_run, mt);
            float alpha = __expf(m_run - mn);
            float rs = 0.f;
            #pragma unroll
            for (int i = 0; i < 16; ++i) {
                float e = __expf(p[i] - mn);
                p[i] = e;
                rs += e;
            }
            rs += __shfl_xor(rs, 32);
            l_run = l_run * alpha + rs;
            m_run = mn;
            oacc[0] *= alpha;
            oacc[1] *= alpha;
            // ---- P -> bf16 B-frags via word swap with partner lane (l ^ 32) ----
            u32 wds[8], xw[8];
            #pragma unroll
            for (int j = 0; j < 8; ++j) {
                u16 a = __builtin_bit_cast(u16, (__bf16)p[2 * j]);
                u16 c = __builtin_bit_cast(u16, (__bf16)p[2 * j + 1]);
                wds[j] = (u32)a | ((u32)c << 16);
            }
            #pragma unroll
            for (int j = 0; j < 8; ++j) xw[j] = (u32)__shfl_xor((int)wds[j], 32);
            union PF { u32 wd[4]; bf16x8 b; } pf[2];
            if (hi == 0) {
                pf[0].wd[0] = wds[0]; pf[0].wd[1] = wds[1]; pf[0].wd[2] = xw[0]; pf[0].wd[3] = xw[1];
                pf[1].wd[0] = wds[4]; pf[1].wd[1] = wds[5]; pf[1].wd[2] = xw[4]; pf[1].wd[3] = xw[5];
            } else {
                pf[0].wd[0] = xw[2]; pf[0].wd[1] = xw[3]; pf[0].wd[2] = wds[2]; pf[0].wd[3] = wds[3];
                pf[1].wd[0] = xw[6]; pf[1].wd[1] = xw[7]; pf[1].wd[2] = wds[6]; pf[1].wd[3] = wds[7];
            }
            // ---- O^T += K^T * P^T  (V == K) ----
            #pragma unroll
            for (int kc = 0; kc < 2; ++kc) {
                #pragma unroll
                for (int db = 0; db < 2; ++db) {
                    int r = db * 32 + l31;
                    int col = (ks + 16 * kc + 8 * hi) ^ ((r & 7) * 8);
                    bf16x8 vf = *reinterpret_cast<const bf16x8*>(tl + r * 64 + col);
                    oacc[db] = __builtin_amdgcn_mfma_f32_32x32x16_bf16(vf, pf[kc].b, oacc[db], 0, 0, 0);
                }
            }
        }
    }

    const float inv = 1.f / l_run;
    u16* op = out + (size_t)(b * 2048 + q) * 1024 + h * 64;
    #pragma unroll
    for (int db = 0; db < 2; ++db) {
        #pragma unroll
        for (int tq = 0; tq < 4; ++tq) {
            ushort4 o;
            o.x = f2bf(oacc[db][tq * 4 + 0] * inv);
            o.y = f2bf(oacc[db][tq * 4 + 1] * inv);
            o.z = f2bf(oacc[db][tq * 4 + 2] * inv);
            o.w = f2bf(oacc[db][tq * 4 + 3] * inv);
            *reinterpret_cast<ushort4*>(op + db * 32 + tq * 8 + hi * 4) = o;
        }
    }
}

// ---------------- launcher ----------------
extern "C" void kernel_launch(void* const* d_in, const int* in_sizes, int n_in,
                              void* d_out, int out_size, void* d_ws, size_t ws_size,
                              hipStream_t stream) {
    const float* x     = (const float*)d_in[0];
    const float* Wq    = (const float*)d_in[1];
    const float* Wk    = (const float*)d_in[2];
    const float* Wproj = (const float*)d_in[3];
    const float* bproj = (const float*)d_in[4];
    const float* ln1g  = (const float*)d_in[5];
    const float* ln1b  = (const float*)d_in[6];
    const float* ln2g  = (const float*)d_in[7];
    const float* ln2b  = (const float*)d_in[8];
    const float* W1    = (const float*)d_in[9];
    const float* b1    = (const float*)d_in[10];
    const float* W2    = (const float*)d_in[11];
    const float* b2    = (const float*)d_in[12];

    char* ws = (char*)d_ws;
    u16*   wqkT   = (u16*)(ws + 0);                     //  4 MiB: 2048x1024
    u16*   wprojT = (u16*)(ws + (4u << 20));            //  2 MiB
    u16*   w1T    = (u16*)(ws + (6u << 20));            //  8 MiB: 4096x1024
    u16*   w2T    = (u16*)(ws + (14u << 20));           //  8 MiB: 1024x4096
    u16*   hbuf   = (u16*)(ws + (22u << 20));           //  8 MiB
    float* xmid   = (float*)(ws + (30u << 20));         // 16 MiB fp32
    u16*   qk     = (u16*)(ws + (46u << 20));           // 16 MiB: 4096x2048
    u16*   ktr    = (u16*)(ws + (62u << 20));           //  8 MiB: 1024x4096 (K^T)
    u16*   attnb  = (u16*)(ws + (70u << 20));           //  8 MiB
    u16*   ff     = (u16*)(ws + (46u << 20));           // 32 MiB, aliases qk+ktr+attnb (dead by then)

    // weight prep (tiled transpose-convert)
    prep_t_kernel<<<dim3(1, 16, 16), 256, 0, stream>>>(Wq, wqkT, 1024, 64);
    prep_t_kernel<<<dim3(1, 16, 16), 256, 0, stream>>>(Wk, wqkT + 1024 * 1024, 1024, 64);
    prep_t_kernel<<<dim3(16, 16, 1), 256, 0, stream>>>(Wproj, wprojT, 1024, 1024);
    prep_t_kernel<<<dim3(64, 16, 1), 256, 0, stream>>>(W1, w1T, 1024, 4096);
    prep_t_kernel<<<dim3(16, 64, 1), 256, 0, stream>>>(W2, w2T, 4096, 1024);

    // LN1
    ln_kernel<<<4096, 256, 0, stream>>>(x, hbuf, ln1g, ln1b);
    // Q|K projection (also emits K^T into ktr)
    gemm_bt<3, u16><<<dim3(16, 32), 256, 0, stream>>>(hbuf, wqkT, qk, nullptr, nullptr, 1024, 2048, ktr);
    // causal attention (V == K)
    attn_kernel<<<512, 256, 0, stream>>>(qk, ktr, attnb);
    // x = x + attn @ Wproj + bproj   (fp32 out)
    gemm_bt<1, float><<<dim3(8, 32), 256, 0, stream>>>(attnb, wprojT, xmid, bproj, x, 1024, 1024, nullptr);
    // LN2
    ln_kernel<<<4096, 256, 0, stream>>>(xmid, hbuf, ln2g, ln2b);
    // ff = relu(h2 @ W1 + b1)  (bf16 out)
    gemm_bt<2, u16><<<dim3(32, 32), 256, 0, stream>>>(hbuf, w1T, ff, b1, nullptr, 1024, 4096, nullptr);
    // out = xmid + ff @ W2 + b2  (fp32 out)
    gemm_bt<1, float><<<dim3(8, 32), 256, 0, stream>>>(ff, w2T, (float*)d_out, b2, xmid, 4096, 1024, nullptr);
}

// Round 3
// 258.625 us; speedup vs baseline: 1.5167x; 1.0625x over previous
//
#include <hip/hip_runtime.h>
#include <stdint.h>

typedef __bf16 bf16x8 __attribute__((ext_vector_type(8)));
typedef float f32x4 __attribute__((ext_vector_type(4)));
typedef float f32x16 __attribute__((ext_vector_type(16)));
typedef unsigned short u16;
typedef unsigned int u32;

union V16 { uint4 u; u16 s[8]; bf16x8 b; };

__device__ __forceinline__ u16 f2bf(float f) {
    u32 u = __builtin_bit_cast(u32, f);
    u = (u + 0x7fffu + ((u >> 16) & 1u)) >> 16;
    return (u16)u;
}

__device__ __forceinline__ void gload16(const u16* g, u16* l) {
    __builtin_amdgcn_global_load_lds(
        (const __attribute__((address_space(1))) unsigned int*)g,
        (__attribute__((address_space(3))) unsigned int*)l,
        16, 0, 0);
}

// ---------------- tiled transpose-convert: src fp32 (Z x R x C) -> dst bf16 (Z x C x R) ----------------
__global__ __launch_bounds__(256)
void prep_t_kernel(const float* __restrict__ src, u16* __restrict__ dst, int R, int C) {
    __shared__ u16 tile[64 * 64];
    const int t = threadIdx.x;
    const int c0 = blockIdx.x * 64, r0 = blockIdx.y * 64;
    const size_t mbase = (size_t)blockIdx.z * R * C;
    {
        const int r = t >> 2, j4 = t & 3;
        #pragma unroll
        for (int j = 0; j < 4; ++j) {
            int c = j4 * 4 + j * 16;
            float4 v = *reinterpret_cast<const float4*>(src + mbase + (size_t)(r0 + r) * C + c0 + c);
            tile[(c + 0) * 64 + (r ^ (((c + 0) & 7) * 8))] = f2bf(v.x);
            tile[(c + 1) * 64 + (r ^ (((c + 1) & 7) * 8))] = f2bf(v.y);
            tile[(c + 2) * 64 + (r ^ (((c + 2) & 7) * 8))] = f2bf(v.z);
            tile[(c + 3) * 64 + (r ^ (((c + 3) & 7) * 8))] = f2bf(v.w);
        }
    }
    __syncthreads();
    {
        const int cc = t >> 2, j4 = t & 3;
        const int sw = (cc & 7) * 8;
        #pragma unroll
        for (int j2 = 0; j2 < 4; ++j2) {
            int rbase = j4 * 16 + j2 * 4;
            ushort4 o;
            o.x = tile[cc * 64 + ((rbase + 0) ^ sw)];
            o.y = tile[cc * 64 + ((rbase + 1) ^ sw)];
            o.z = tile[cc * 64 + ((rbase + 2) ^ sw)];
            o.w = tile[cc * 64 + ((rbase + 3) ^ sw)];
            *reinterpret_cast<ushort4*>(dst + mbase + (size_t)(c0 + cc) * R + r0 + rbase) = o;
        }
    }
}

// ---------------- layernorm: fp32 (rows x 1024) -> bf16 ----------------
__global__ __launch_bounds__(256)
void ln_kernel(const float* __restrict__ x, u16* __restrict__ out,
               const float* __restrict__ gw, const float* __restrict__ bw) {
    __shared__ float red[8];
    int row = blockIdx.x, t = threadIdx.x;
    float4 v = reinterpret_cast<const float4*>(x + (size_t)row * 1024)[t];
    float s = v.x + v.y + v.z + v.w;
    float sq = v.x * v.x + v.y * v.y + v.z * v.z + v.w * v.w;
    for (int o = 32; o > 0; o >>= 1) { s += __shfl_down(s, o); sq += __shfl_down(sq, o); }
    if ((t & 63) == 0) { red[t >> 6] = s; red[4 + (t >> 6)] = sq; }
    __syncthreads();
    float S  = red[0] + red[1] + red[2] + red[3];
    float SQ = red[4] + red[5] + red[6] + red[7];
    float mean = S * (1.f / 1024.f);
    float var  = SQ * (1.f / 1024.f) - mean * mean;
    float rstd = rsqrtf(var + 1e-5f);
    float4 g4 = reinterpret_cast<const float4*>(gw)[t];
    float4 b4 = reinterpret_cast<const float4*>(bw)[t];
    ushort4 o;
    o.x = f2bf((v.x - mean) * rstd * g4.x + b4.x);
    o.y = f2bf((v.y - mean) * rstd * g4.y + b4.y);
    o.z = f2bf((v.z - mean) * rstd * g4.z + b4.z);
    o.w = f2bf((v.w - mean) * rstd * g4.w + b4.w);
    reinterpret_cast<ushort4*>(out + (size_t)row * 1024)[t] = o;
}

// ---------------- 128x128 GEMM (kept for proj + fallback) ----------------
template<int EPI, typename OT>
__global__ __launch_bounds__(256)
void gemm_bt(const u16* __restrict__ A, const u16* __restrict__ B,
             OT* __restrict__ C, const float* __restrict__ bias,
             const float* __restrict__ res, int K, int N, u16* __restrict__ ktr) {
    __shared__ u16 Al[128 * 64];
    __shared__ u16 Bl[128 * 64];
    const int t = threadIdx.x;
    const int lane = t & 63;
    const int w = t >> 6;
    const int wm = w >> 1, wn = w & 1;
    const int l15 = lane & 15, gq = lane >> 4;
    const int gx = gridDim.x;
    const int nwg = gx * gridDim.y;
    const int bid = blockIdx.y * gx + blockIdx.x;
    const int sw = ((nwg & 7) == 0) ? ((bid & 7) * (nwg >> 3) + (bid >> 3)) : bid;
    const int col0 = (sw % gx) * 128;
    const int row0 = (sw / gx) * 128;

    f32x4 acc[4][4] = {};

    const int nkb = K >> 6;
    for (int kb = 0; kb < nkb; ++kb) {
        #pragma unroll
        for (int i = 0; i < 4; ++i) {
            int slot = i * 256 + t;
            int r = slot >> 3;
            int g = (slot & 7) ^ (r & 7);       // pre-swizzled source granule
            gload16(A + (size_t)(row0 + r) * K + kb * 64 + g * 8, Al + slot * 8);
            gload16(B + (size_t)(col0 + r) * K + kb * 64 + g * 8, Bl + slot * 8);
        }
        __syncthreads();
        #pragma unroll
        for (int s = 0; s < 2; ++s) {
            bf16x8 af[4], bfr[4];
            #pragma unroll
            for (int mi = 0; mi < 4; ++mi) {
                int rl = wm * 64 + mi * 16 + l15;
                int ba = rl * 128 + ((s * 64 + gq * 16) ^ ((rl & 7) << 4));
                af[mi] = *reinterpret_cast<const bf16x8*>(reinterpret_cast<const char*>(Al) + ba);
            }
            #pragma unroll
            for (int ni = 0; ni < 4; ++ni) {
                int rl = wn * 64 + ni * 16 + l15;
                int ba = rl * 128 + ((s * 64 + gq * 16) ^ ((rl & 7) << 4));
                bfr[ni] = *reinterpret_cast<const bf16x8*>(reinterpret_cast<const char*>(Bl) + ba);
            }
            #pragma unroll
            for (int mi = 0; mi < 4; ++mi)
                #pragma unroll
                for (int ni = 0; ni < 4; ++ni)
                    acc[mi][ni] = __builtin_amdgcn_mfma_f32_16x16x32_bf16(af[mi], bfr[ni], acc[mi][ni], 0, 0, 0);
        }
        __syncthreads();
    }

    #pragma unroll
    for (int mi = 0; mi < 4; ++mi) {
        #pragma unroll
        for (int ni = 0; ni < 4; ++ni) {
            int gcol = col0 + wn * 64 + ni * 16 + l15;
            int grow0 = row0 + wm * 64 + mi * 16 + gq * 4;
            #pragma unroll
            for (int r = 0; r < 4; ++r) {
                int grow = grow0 + r;
                float v = acc[mi][ni][r];
                if constexpr (EPI == 1 || EPI == 2) v += bias[gcol];
                if constexpr (EPI == 1) v += res[(size_t)grow * N + gcol];
                if constexpr (EPI == 2) v = fmaxf(v, 0.f);
                if constexpr (sizeof(OT) == 4) C[(size_t)grow * N + gcol] = v;
                else                           C[(size_t)grow * N + gcol] = f2bf(v);
            }
        }
    }
}

// ---------------- 256x256 8-phase GEMM (T1+T2+T3+T4+T5) ----------------
// EPI: 0 = plain store; 2 = +bias +relu -> bf16; 3 = plain bf16 + ktr side-write
#define DS_A(MH) \
  _Pragma("unroll") \
  for (int mi = 0; mi < 4; ++mi) { \
    const int rl = wm * 128 + (MH) * 64 + mi * 16 + l15; \
    const char* rp = abase + rl * 128; \
    const int sw2 = (rl & 7) << 4; \
    af[mi][0] = *reinterpret_cast<const bf16x8*>(rp + ((gq * 16) ^ sw2)); \
    af[mi][1] = *reinterpret_cast<const bf16x8*>(rp + ((64 + gq * 16) ^ sw2)); \
  }

#define DS_B(NH) \
  _Pragma("unroll") \
  for (int ni = 0; ni < 2; ++ni) { \
    const int rl = wn * 64 + (NH) * 32 + ni * 16 + l15; \
    const char* rp = bbase + rl * 128; \
    const int sw2 = (rl & 7) << 4; \
    bfr[ni][0] = *reinterpret_cast<const bf16x8*>(rp + ((gq * 16) ^ sw2)); \
    bfr[ni][1] = *reinterpret_cast<const bf16x8*>(rp + ((64 + gq * 16) ^ sw2)); \
  }

#define ST_A(HALF, KP, DB) \
  _Pragma("unroll") \
  for (int i = 0; i < 2; ++i) { \
    const int idx = i * 512 + t; const int rs = idx >> 3; const int kc = idx & 7; \
    const int row = (rs & 63) + ((rs >> 6) << 7) + (HALF) * 64; \
    gload16(Ag + (size_t)(row0 + row) * Kf + (KP) + ((kc ^ (row & 7)) << 3), (DB) + row * 64 + kc * 8); \
  }

#define ST_B(HALF, KP, DB) \
  _Pragma("unroll") \
  for (int i = 0; i < 2; ++i) { \
    const int idx = i * 512 + t; const int rs = idx >> 3; const int kc = idx & 7; \
    const int row = (rs & 31) + ((rs >> 5) << 6) + (HALF) * 32; \
    gload16(Bg + (size_t)(col0 + row) * Kf + (KP) + ((kc ^ (row & 7)) << 3), (DB) + row * 64 + kc * 8); \
  }

#define MFMA_Q(MH, NH) \
  _Pragma("unroll") \
  for (int mi = 0; mi < 4; ++mi) { \
    _Pragma("unroll") \
    for (int ni = 0; ni < 2; ++ni) { \
      acc[MH][mi][NH][ni] = __builtin_amdgcn_mfma_f32_16x16x32_bf16(af[mi][0], bfr[ni][0], acc[MH][mi][NH][ni], 0, 0, 0); \
      acc[MH][mi][NH][ni] = __builtin_amdgcn_mfma_f32_16x16x32_bf16(af[mi][1], bfr[ni][1], acc[MH][mi][NH][ni], 0, 0, 0); \
    } \
  }

#define WAITV(N) asm volatile("s_waitcnt vmcnt(" #N ")" ::: "memory")
#define BAR() __builtin_amdgcn_s_barrier()
#define PRIO1() __builtin_amdgcn_s_setprio(1)
#define PRIO0() __builtin_amdgcn_s_setprio(0)

template<int EPI, typename OT>
__global__ __launch_bounds__(512, 2)
void gemm256(const u16* __restrict__ A, const u16* __restrict__ B, OT* __restrict__ C,
             const float* __restrict__ bias, const float* __restrict__ res,
             int Kf, int KC, int N, u16* __restrict__ ktr) {
    __shared__ u16 AL[2][16384];
    __shared__ u16 BL[2][16384];
    const int t = threadIdx.x;
    const int lane = t & 63;
    const int w = t >> 6;
    const int wm = w >> 2, wn = w & 3;
    const int l15 = lane & 15, gq = lane >> 4;
    const int gx = gridDim.x;
    const int nwg = gx * gridDim.y;
    const int bid = blockIdx.y * gx + blockIdx.x;
    const int sw = ((nwg & 7) == 0) ? ((bid & 7) * (nwg >> 3) + (bid >> 3)) : bid;
    const int col0 = (sw % gx) * 256;
    const int row0 = (sw / gx) * 256;
    const int kbase = blockIdx.z * KC;
    const u16* Ag = A;
    const u16* Bg = B;

    f32x4 acc[2][4][2][2] = {};
    bf16x8 af[4][2], bfr[2][2];

    const int NT = KC >> 6;
    // prologue: stage tile 0 into buf 0; issue order UA0, UB0, UB1, UA1
    { u16* An = &AL[0][0]; u16* Bn = &BL[0][0];
      ST_A(0, kbase, An); ST_B(0, kbase, Bn); ST_B(1, kbase, Bn); ST_A(1, kbase, An); }
    WAITV(4);
    BAR();

    for (int tI = 0; tI < NT - 1; ++tI) {
        const int c = tI & 1;
        const char* abase = reinterpret_cast<const char*>(&AL[c][0]);
        const char* bbase = reinterpret_cast<const char*>(&BL[c][0]);
        u16* An = &AL[c ^ 1][0];
        u16* Bn = &BL[c ^ 1][0];
        const int kn = kbase + (tI + 1) * 64;
        // phase 1: quadrant (m0,n0); stage UA0(t+1); protect UB1(t)
        DS_A(0); DS_B(0);
        ST_A(0, kn, An);
        WAITV(4); BAR();
        PRIO1(); MFMA_Q(0, 0); PRIO0();
        BAR();
        // phase 2: quadrant (m0,n1); stage UB0(t+1); protect UA1(t)
        DS_B(1);
        ST_B(0, kn, Bn);
        WAITV(4); BAR();
        PRIO1(); MFMA_Q(0, 1); PRIO0();
        BAR();
        // phase 3: quadrant (m1,n0); stage UB1(t+1); nothing new to protect
        DS_A(1); DS_B(0);
        ST_B(1, kn, Bn);
        BAR();
        PRIO1(); MFMA_Q(1, 0); PRIO0();
        BAR();
        // phase 4: quadrant (m1,n1); stage UA1(t+1); protect UA0/UB0(t+1)
        DS_B(1);
        ST_A(1, kn, An);
        WAITV(4); BAR();
        PRIO1(); MFMA_Q(1, 1); PRIO0();
        BAR();
    }
    // peeled last tile (no staging; drain 2 -> 0)
    {
        const int c = (NT - 1) & 1;
        const char* abase = reinterpret_cast<const char*>(&AL[c][0]);
        const char* bbase = reinterpret_cast<const char*>(&BL[c][0]);
        DS_A(0); DS_B(0);
        WAITV(2); BAR();
        PRIO1(); MFMA_Q(0, 0); PRIO0();
        BAR();
        DS_B(1);
        WAITV(0); BAR();
        PRIO1(); MFMA_Q(0, 1); PRIO0();
        BAR();
        DS_A(1); DS_B(0);
        BAR();
        PRIO1(); MFMA_Q(1, 0); PRIO0();
        BAR();
        DS_B(1);
        PRIO1(); MFMA_Q(1, 1); PRIO0();
    }

    const size_t Crow0 = (size_t)blockIdx.z * ((size_t)gridDim.y * 256);
    #pragma unroll
    for (int mh = 0; mh < 2; ++mh)
    #pragma unroll
    for (int mi = 0; mi < 4; ++mi)
    #pragma unroll
    for (int nh = 0; nh < 2; ++nh)
    #pragma unroll
    for (int ni = 0; ni < 2; ++ni) {
        const int gcol = col0 + wn * 64 + nh * 32 + ni * 16 + l15;
        const int grow0 = row0 + wm * 128 + mh * 64 + mi * 16 + gq * 4;
        f32x4 v = acc[mh][mi][nh][ni];
        if constexpr (EPI == 2) {
            const float bb = bias[gcol];
            v[0] += bb; v[1] += bb; v[2] += bb; v[3] += bb;
        }
        #pragma unroll
        for (int r = 0; r < 4; ++r) {
            const size_t o = (Crow0 + grow0 + r) * N + gcol;
            float x = v[r];
            if constexpr (EPI == 2) x = fmaxf(x, 0.f);
            if constexpr (sizeof(OT) == 4) C[o] = x;
            else                           C[o] = f2bf(x);
        }
        if constexpr (EPI == 3) {
            if (gcol >= 1024) {
                ushort4 k4;
                k4.x = f2bf(v[0]); k4.y = f2bf(v[1]); k4.z = f2bf(v[2]); k4.w = f2bf(v[3]);
                *reinterpret_cast<ushort4*>(ktr + (size_t)(gcol - 1024) * 4096 + grow0) = k4;
            }
        }
    }
}

// ---------------- split-K reduce: out = xmid + b2 + sum(partials) ----------------
__global__ __launch_bounds__(256)
void reduce4_kernel(const float4* __restrict__ p0, const float4* __restrict__ p1,
                    const float4* __restrict__ p2, const float4* __restrict__ p3,
                    const float4* __restrict__ xm, const float* __restrict__ b2,
                    float4* __restrict__ out) {
    const int i = blockIdx.x * 256 + threadIdx.x;
    float4 a = p0[i], b = p1[i], c = p2[i], d = p3[i], x = xm[i];
    const float4 bb = *reinterpret_cast<const float4*>(b2 + ((i & 255) << 2));
    float4 o;
    o.x = x.x + bb.x + a.x + b.x + c.x + d.x;
    o.y = x.y + bb.y + a.y + b.y + c.y + d.y;
    o.z = x.z + bb.z + a.z + b.z + c.z + d.z;
    o.w = x.w + bb.w + a.w + b.w + c.w + d.w;
    out[i] = o;
}

// ---------------- causal flash attention, V == K, 4 waves x 32 q-rows ----------------
__global__ __launch_bounds__(256)
void attn_kernel(const u16* __restrict__ qk, const u16* __restrict__ ktr, u16* __restrict__ out) {
    __shared__ u16 Kl[2][64 * 64];   // K rows  [k][d], swizzled
    __shared__ u16 Tl[2][64 * 64];   // K^T     [d][k], swizzled
    const int t = threadIdx.x;
    const int lane = t & 63;
    const int w = t >> 6;
    const int l31 = lane & 31, hi = lane >> 5;
    const int flat = blockIdx.x;
    const int bh = flat & 31;
    const int tt = flat >> 5;                      // 0..15
    const int qb = (tt < 8) ? tt : 23 - tt;        // pair heavy+light on same CU
    const int b = bh >> 4, h = bh & 15;
    const int q0w = qb * 128 + w * 32;
    const int q = q0w + l31;
    const u16* Qp = qk + (size_t)b * 2048 * 2048 + h * 64;
    const u16* Kp = Qp + 1024;
    const u16* Tp = ktr + (size_t)h * 64 * 4096 + (size_t)b * 2048;

    bf16x8 qf[4];
    #pragma unroll
    for (int s = 0; s < 4; ++s)
        qf[s] = *reinterpret_cast<const bf16x8*>(Qp + (size_t)q * 2048 + s * 16 + hi * 8);

    f32x16 oacc[2] = {};
    float m_run = -3.0e38f, l_run = 0.f;
    const int qwmax = q0w + 31;
    const int nt = (qb * 128 + 128) >> 6;          // number of 64-wide k stages

    {
        #pragma unroll
        for (int i = 0; i < 2; ++i) {
            int slot = i * 256 + t;
            int r = slot >> 3;
            int g = (slot & 7) ^ (r & 7);
            gload16(Kp + (size_t)r * 2048 + g * 8, &Kl[0][0] + slot * 8);
            gload16(Tp + (size_t)r * 4096 + g * 8, &Tl[0][0] + slot * 8);
        }
    }

    for (int kt = 0; kt < nt; ++kt) {
        const int cur = kt & 1;
        __syncthreads();
        if (kt + 1 < nt) {
            int k0 = (kt + 1) * 64;
            #pragma unroll
            for (int i = 0; i < 2; ++i) {
                int slot = i * 256 + t;
                int r = slot >> 3;
                int g = (slot & 7) ^ (r & 7);
                gload16(Kp + (size_t)(k0 + r) * 2048 + g * 8, &Kl[cur ^ 1][0] + slot * 8);
                gload16(Tp + (size_t)r * 4096 + k0 + g * 8, &Tl[cur ^ 1][0] + slot * 8);
            }
        }
        const u16* kl = &Kl[cur][0];
        const u16* tl = &Tl[cur][0];
        #pragma unroll
        for (int s2 = 0; s2 < 2; ++s2) {
            const int ks = s2 * 32;
            const int kbase = kt * 64 + ks;
            if (kbase > qwmax) continue;
            f32x16 st = {};
            #pragma unroll
            for (int s = 0; s < 4; ++s) {
                int r = ks + l31;
                int col = (16 * s + 8 * hi) ^ ((r & 7) * 8);
                bf16x8 kf = *reinterpret_cast<const bf16x8*>(kl + r * 64 + col);
                st = __builtin_amdgcn_mfma_f32_32x32x16_bf16(kf, qf[s], st, 0, 0, 0);
            }
            float p[16];
            float mt = -3.0e38f;
            if (kbase + 31 <= q0w) {
                #pragma unroll
                for (int i = 0; i < 16; ++i) { p[i] = st[i] * 0.125f; mt = fmaxf(mt, p[i]); }
            } else {
                #pragma unroll
                for (int i = 0; i < 16; ++i) {
                    int kloc = (i & 3) + 8 * (i >> 2) + 4 * hi;
                    float v = st[i] * 0.125f;
                    v = (kbase + kloc <= q) ? v : -3.0e38f;
                    p[i] = v;
                    mt = fmaxf(mt, v);
                }
            }
            mt = fmaxf(mt, __shfl_xor(mt, 32));
            float mn = fmaxf(m_run, mt);
            float alpha = __expf(m_run - mn);
            float rs = 0.f;
            #pragma unroll
            for (int i = 0; i < 16; ++i) {
                float e = __expf(p[i] - mn);
                p[i] = e;
                rs += e;
            }
            rs += __shfl_xor(rs, 32);
            l_run = l_run * alpha + rs;
            m_run = mn;
            oacc[0] *= alpha;
            oacc[1] *= alpha;
            u32 wds[8], xw[8];
            #pragma unroll
            for (int j = 0; j < 8; ++j) {
                u16 a = __builtin_bit_cast(u16, (__bf16)p[2 * j]);
                u16 c = __builtin_bit_cast(u16, (__bf16)p[2 * j + 1]);
                wds[j] = (u32)a | ((u32)c << 16);
            }
            #pragma unroll
            for (int j = 0; j < 8; ++j) xw[j] = (u32)__shfl_xor((int)wds[j], 32);
            union PF { u32 wd[4]; bf16x8 b; } pf[2];
            if (hi == 0) {
                pf[0].wd[0] = wds[0]; pf[0].wd[1] = wds[1]; pf[0].wd[2] = xw[0]; pf[0].wd[3] = xw[1];
                pf[1].wd[0] = wds[4]; pf[1].wd[1] = wds[5]; pf[1].wd[2] = xw[4]; pf[1].wd[3] = xw[5];
            } else {
                pf[0].wd[0] = xw[2]; pf[0].wd[1] = xw[3]; pf[0].wd[2] = wds[2]; pf[0].wd[3] = wds[3];
                pf[1].wd[0] = xw[6]; pf[1].wd[1] = xw[7]; pf[1].wd[2] = wds[6]; pf[1].wd[3] = wds[7];
            }
            #pragma unroll
            for (int kc = 0; kc < 2; ++kc) {
                #pragma unroll
                for (int db = 0; db < 2; ++db) {
                    int r = db * 32 + l31;
                    int col = (ks + 16 * kc + 8 * hi) ^ ((r & 7) * 8);
                    bf16x8 vf = *reinterpret_cast<const bf16x8*>(tl + r * 64 + col);
                    oacc[db] = __builtin_amdgcn_mfma_f32_32x32x16_bf16(vf, pf[kc].b, oacc[db], 0, 0, 0);
                }
            }
        }
    }

    const float inv = 1.f / l_run;
    u16* op = out + (size_t)(b * 2048 + q) * 1024 + h * 64;
    #pragma unroll
    for (int db = 0; db < 2; ++db) {
        #pragma unroll
        for (int tq = 0; tq < 4; ++tq) {
            ushort4 o;
            o.x = f2bf(oacc[db][tq * 4 + 0] * inv);
            o.y = f2bf(oacc[db][tq * 4 + 1] * inv);
            o.z = f2bf(oacc[db][tq * 4 + 2] * inv);
            o.w = f2bf(oacc[db][tq * 4 + 3] * inv);
            *reinterpret_cast<ushort4*>(op + db * 32 + tq * 8 + hi * 4) = o;
        }
    }
}

// ---------------- launcher ----------------
extern "C" void kernel_launch(void* const* d_in, const int* in_sizes, int n_in,
                              void* d_out, int out_size, void* d_ws, size_t ws_size,
                              hipStream_t stream) {
    const float* x     = (const float*)d_in[0];
    const float* Wq    = (const float*)d_in[1];
    const float* Wk    = (const float*)d_in[2];
    const float* Wproj = (const float*)d_in[3];
    const float* bproj = (const float*)d_in[4];
    const float* ln1g  = (const float*)d_in[5];
    const float* ln1b  = (const float*)d_in[6];
    const float* ln2g  = (const float*)d_in[7];
    const float* ln2b  = (const float*)d_in[8];
    const float* W1    = (const float*)d_in[9];
    const float* b1    = (const float*)d_in[10];
    const float* W2    = (const float*)d_in[11];
    const float* b2    = (const float*)d_in[12];

    char* ws = (char*)d_ws;
    u16*   wqkT   = (u16*)(ws + 0);                     //  4 MiB: 2048x1024
    u16*   wprojT = (u16*)(ws + (4ull << 20));          //  2 MiB
    u16*   w1T    = (u16*)(ws + (6ull << 20));          //  8 MiB: 4096x1024
    u16*   w2T    = (u16*)(ws + (14ull << 20));         //  8 MiB: 1024x4096
    u16*   hbuf   = (u16*)(ws + (22ull << 20));         //  8 MiB
    float* xmid   = (float*)(ws + (30ull << 20));       // 16 MiB fp32
    u16*   qk     = (u16*)(ws + (46ull << 20));         // 16 MiB: 4096x2048
    u16*   ktr    = (u16*)(ws + (62ull << 20));         //  8 MiB: 1024x4096 (K^T)
    u16*   attnb  = (u16*)(ws + (70ull << 20));         //  8 MiB
    u16*   ff     = (u16*)(ws + (46ull << 20));         // 32 MiB, aliases qk+ktr+attnb (dead by then)
    float* part   = (float*)(ws + (78ull << 20));       // 64 MiB: 4 x 4096x1024 fp32 partials
    const bool fastW2 = ws_size >= (142ull << 20);

    // weight prep (tiled transpose-convert)
    prep_t_kernel<<<dim3(1, 16, 16), 256, 0, stream>>>(Wq, wqkT, 1024, 64);
    prep_t_kernel<<<dim3(1, 16, 16), 256, 0, stream>>>(Wk, wqkT + 1024 * 1024, 1024, 64);
    prep_t_kernel<<<dim3(16, 16, 1), 256, 0, stream>>>(Wproj, wprojT, 1024, 1024);
    prep_t_kernel<<<dim3(64, 16, 1), 256, 0, stream>>>(W1, w1T, 1024, 4096);
    prep_t_kernel<<<dim3(16, 64, 1), 256, 0, stream>>>(W2, w2T, 4096, 1024);

    // LN1
    ln_kernel<<<4096, 256, 0, stream>>>(x, hbuf, ln1g, ln1b);
    // Q|K projection (also emits K^T into ktr)
    gemm256<3, u16><<<dim3(8, 16, 1), 512, 0, stream>>>(hbuf, wqkT, qk, nullptr, nullptr, 1024, 1024, 2048, ktr);
    // causal attention (V == K)
    attn_kernel<<<512, 256, 0, stream>>>(qk, ktr, attnb);
    // x = x + attn @ Wproj + bproj   (fp32 out)
    gemm_bt<1, float><<<dim3(8, 32), 256, 0, stream>>>(attnb, wprojT, xmid, bproj, x, 1024, 1024, nullptr);
    // LN2
    ln_kernel<<<4096, 256, 0, stream>>>(xmid, hbuf, ln2g, ln2b);
    // ff = relu(h2 @ W1 + b1)  (bf16 out)
    gemm256<2, u16><<<dim3(16, 16, 1), 512, 0, stream>>>(hbuf, w1T, ff, b1, nullptr, 1024, 1024, 4096, nullptr);
    // out = xmid + ff @ W2 + b2  (fp32 out)
    if (fastW2) {
        gemm256<0, float><<<dim3(4, 16, 4), 512, 0, stream>>>(ff, w2T, part, nullptr, nullptr, 4096, 1024, 1024, nullptr);
        reduce4_kernel<<<4096, 256, 0, stream>>>(
            (const float4*)part, (const float4*)(part + 4194304),
            (const float4*)(part + 2 * 4194304), (const float4*)(part + 3 * 4194304),
            (const float4*)xmid, b2, (float4*)d_out);
    } else {
        gemm_bt<1, float><<<dim3(8, 32), 256, 0, stream>>>(ff, w2T, (float*)d_out, b2, xmid, 4096, 1024, nullptr);
    }
}